// Round 7
// baseline (188.465 us; speedup 1.0000x reference)
//
#include <hip/hip_runtime.h>

// Problem dims (fixed by setup_inputs)
constexpr int B = 2, C = 32, H = 96, W = 160, D = 32;
constexpr int HW = H * W;            // 15360
constexpr int NP = B * H * W;        // 30720 pixels
constexpr int WG = W / 4;            // 40 four-wide output groups per row
constexpr float EPS = 1e-12f;

// ---------------------------------------------------------------------------
// DIAGNOSTIC ROUND: R4 kernels with in-kernel repeat loops so both kernels
// exceed the 70us harness fills and appear in rocprof top-5.
//   stage1 x5  (~140us expected) -> FETCH_SIZE tells HBM-vs-L3 residency of k
//   stage2 x16 (~100us expected) -> marginal pass cost = true T2
// Accumulate-and-scale keeps every pass's loads live (no DCE, rule #17);
// opaque pert prevents load CSE across passes. Output numerically ~identical.
// ---------------------------------------------------------------------------
constexpr int R1 = 5;
constexpr int R2 = 16;

__global__ __launch_bounds__(256) void dav_stage1(
    const float* __restrict__ q, const float* __restrict__ k,
    float2* __restrict__ sn, float* __restrict__ nq) {
  int gt = blockIdx.x * 256 + threadIdx.x;
  int pixel = gt >> 4;   // pixel index in [0, NP)
  int sub = gt & 15;
  int dg = sub >> 1;     // d-group [0,8)
  int ch = sub & 1;      // c-half {0,1}
  int b  = pixel / HW;
  int hw = pixel - b * HW;

  const float* kbase = k + ((size_t)(b * C + ch * 16) * HW + hw) * D + dg * 4;
  const float* qbase = q + (size_t)(b * C + ch * 16) * HW + hw;

  float4 s4 = make_float4(0.f, 0.f, 0.f, 0.f);
  float4 n4 = make_float4(0.f, 0.f, 0.f, 0.f);
  float  nqv = 0.f;

  int pert = 0;                      // stays 0; opaque to the compiler
#pragma unroll 1
  for (int r = 0; r < R1; ++r) {
    asm volatile("" : "+v"(pert));   // forbid cross-pass load CSE
    const float* kb = kbase + pert;
    const float* qb = qbase + pert;
#pragma unroll
    for (int c = 0; c < 16; ++c) {
      float4 k4 = *reinterpret_cast<const float4*>(kb + (size_t)c * HW * D);
      float  qc = qb[(size_t)c * HW];
      s4.x = fmaf(qc, k4.x, s4.x);
      s4.y = fmaf(qc, k4.y, s4.y);
      s4.z = fmaf(qc, k4.z, s4.z);
      s4.w = fmaf(qc, k4.w, s4.w);
      n4.x = fmaf(k4.x, k4.x, n4.x);
      n4.y = fmaf(k4.y, k4.y, n4.y);
      n4.z = fmaf(k4.z, k4.z, n4.z);
      n4.w = fmaf(k4.w, k4.w, n4.w);
      nqv  = fmaf(qc, qc, nqv);
    }
  }

  s4.x += __shfl_xor(s4.x, 1);
  s4.y += __shfl_xor(s4.y, 1);
  s4.z += __shfl_xor(s4.z, 1);
  s4.w += __shfl_xor(s4.w, 1);
  n4.x += __shfl_xor(n4.x, 1);
  n4.y += __shfl_xor(n4.y, 1);
  n4.z += __shfl_xor(n4.z, 1);
  n4.w += __shfl_xor(n4.w, 1);
  nqv  += __shfl_xor(nqv, 1);

  constexpr float inv1 = 1.0f / R1;
  if (ch == 0) {
    size_t obase = ((size_t)(b * D + dg * 4)) * HW + hw;  // planar (B,D,H,W)
    sn[obase]          = make_float2(s4.x * inv1, n4.x * inv1);
    sn[obase + HW]     = make_float2(s4.y * inv1, n4.y * inv1);
    sn[obase + 2 * HW] = make_float2(s4.z * inv1, n4.z * inv1);
    sn[obase + 3 * HW] = make_float2(s4.w * inv1, n4.w * inv1);
    if (dg == 0) nq[pixel] = nqv * inv1;
  }
}

__global__ __launch_bounds__(256) void dav_stage2(
    const float2* __restrict__ sn, const float* __restrict__ nq,
    float* __restrict__ out) {
  int idx = blockIdx.x * 256 + threadIdx.x;
  if (idx >= B * D * H * WG) return;
  int g  = idx % WG;
  int h  = (idx / WG) % H;
  int bd = idx / (WG * H);   // b*D + d
  int b  = bd / D;
  int w0 = g * 4;

  float oacc[4] = {0.f, 0.f, 0.f, 0.f};
  int pert = 0;                      // stays 0; opaque to the compiler
#pragma unroll 1
  for (int r = 0; r < R2; ++r) {
    asm volatile("" : "+v"(pert));
    const float2* plane  = sn + (size_t)bd * HW + pert;
    const float*  qplane = nq + (size_t)b * HW + pert;

    float csS[6] = {0.f, 0.f, 0.f, 0.f, 0.f, 0.f};
    float csN[6] = {0.f, 0.f, 0.f, 0.f, 0.f, 0.f};
    float csQ[6] = {0.f, 0.f, 0.f, 0.f, 0.f, 0.f};
#pragma unroll
    for (int rr = -1; rr <= 1; ++rr) {
      int hh = h + rr;
      if (hh < 0 || hh >= H) continue;
      const float2* row  = plane + hh * W;
      const float*  qrow = qplane + hh * W;
#pragma unroll
      for (int i = 0; i < 6; ++i) {
        int c = w0 - 1 + i;
        if (c >= 0 && c < W) {
          float2 v = row[c];
          csS[i] += v.x;
          csN[i] += v.y;
          csQ[i] += qrow[c];
        }
      }
    }
#pragma unroll
    for (int i = 0; i < 4; ++i) {
      float dot = csS[i] + csS[i + 1] + csS[i + 2];
      float k2  = csN[i] + csN[i + 1] + csN[i + 2];
      float q2  = csQ[i] + csQ[i + 1] + csQ[i + 2];
      float dq  = fmaxf(sqrtf(q2), EPS);
      float dk  = fmaxf(sqrtf(k2), EPS);
      oacc[i] += dot / (dq * dk);
    }
  }

  constexpr float inv2 = 1.0f / R2;
  *reinterpret_cast<float4*>(out + (size_t)bd * HW + h * W + w0) =
      make_float4(oacc[0] * inv2, oacc[1] * inv2, oacc[2] * inv2,
                  oacc[3] * inv2);
}

extern "C" void kernel_launch(void* const* d_in, const int* in_sizes, int n_in,
                              void* d_out, int out_size, void* d_ws, size_t ws_size,
                              hipStream_t stream) {
  const float* q = (const float*)d_in[0];               // (B,C,H,W)
  const float* k = (const float*)d_in[1];               // (B,C,H,W,D)
  float* out = (float*)d_out;                           // (B,D,H,W)

  // Workspace layout: sn (float2, NP*D) | nq (float, NP)
  float2* sn = (float2*)d_ws;                           // 7.86 MB
  float*  nq = (float*)(sn + (size_t)NP * D);           // 0.12 MB

  {
    int threads = NP * 16;                  // 16 lanes per pixel -> 491520
    int blocks = threads / 256;             // 1920 (exact)
    dav_stage1<<<blocks, 256, 0, stream>>>(q, k, sn, nq);
  }
  {
    int n = B * D * H * WG;                 // 245760
    int blocks = (n + 255) / 256;           // 960
    dav_stage2<<<blocks, 256, 0, stream>>>(sn, nq, out);
  }
}

// Round 8
// 32.932 us; speedup vs baseline: 5.7228x; 5.7228x over previous
//
#include <hip/hip_runtime.h>

// Problem dims (fixed by setup_inputs)
constexpr int B = 2, C = 32, H = 96, W = 160, D = 32;
constexpr int HW = H * W;            // 15360
constexpr int NP = B * H * W;        // 30720 pixels
constexpr int WG2 = W / 2;           // 80 two-wide output groups per row
constexpr float EPS = 1e-12f;

// ---------------------------------------------------------------------------
// Stage 1: per-pixel channel reductions (byte-identical to the 37.7us R4
// version -- single-variable round, only stage 2 changes).
//   sn[(b*D+d)*HW + hw] = { sum_c q*k , sum_c k*k }   (interleaved float2)
//   nq[b*HW + hw]       = sum_c q*q
// ---------------------------------------------------------------------------
__global__ __launch_bounds__(256) void dav_stage1(
    const float* __restrict__ q, const float* __restrict__ k,
    float2* __restrict__ sn, float* __restrict__ nq) {
  int gt = blockIdx.x * 256 + threadIdx.x;
  int pixel = gt >> 4;   // pixel index in [0, NP)
  int sub = gt & 15;
  int dg = sub >> 1;     // d-group [0,8)
  int ch = sub & 1;      // c-half {0,1}
  int b  = pixel / HW;
  int hw = pixel - b * HW;

  const float* kbase = k + ((size_t)(b * C + ch * 16) * HW + hw) * D + dg * 4;
  const float* qbase = q + (size_t)(b * C + ch * 16) * HW + hw;

  float4 s4 = make_float4(0.f, 0.f, 0.f, 0.f);
  float4 n4 = make_float4(0.f, 0.f, 0.f, 0.f);
  float  nqv = 0.f;

#pragma unroll
  for (int c = 0; c < 16; ++c) {
    float4 k4 = *reinterpret_cast<const float4*>(kbase + (size_t)c * HW * D);
    float  qc = qbase[(size_t)c * HW];
    s4.x = fmaf(qc, k4.x, s4.x);
    s4.y = fmaf(qc, k4.y, s4.y);
    s4.z = fmaf(qc, k4.z, s4.z);
    s4.w = fmaf(qc, k4.w, s4.w);
    n4.x = fmaf(k4.x, k4.x, n4.x);
    n4.y = fmaf(k4.y, k4.y, n4.y);
    n4.z = fmaf(k4.z, k4.z, n4.z);
    n4.w = fmaf(k4.w, k4.w, n4.w);
    nqv  = fmaf(qc, qc, nqv);
  }

  s4.x += __shfl_xor(s4.x, 1);
  s4.y += __shfl_xor(s4.y, 1);
  s4.z += __shfl_xor(s4.z, 1);
  s4.w += __shfl_xor(s4.w, 1);
  n4.x += __shfl_xor(n4.x, 1);
  n4.y += __shfl_xor(n4.y, 1);
  n4.z += __shfl_xor(n4.z, 1);
  n4.w += __shfl_xor(n4.w, 1);
  nqv  += __shfl_xor(nqv, 1);

  if (ch == 0) {
    size_t obase = ((size_t)(b * D + dg * 4)) * HW + hw;  // planar (B,D,H,W)
    sn[obase]          = make_float2(s4.x, n4.x);
    sn[obase + HW]     = make_float2(s4.y, n4.y);
    sn[obase + 2 * HW] = make_float2(s4.z, n4.z);
    sn[obase + 3 * HW] = make_float2(s4.w, n4.w);
    if (dg == 0) nq[pixel] = nqv;
  }
}

// ---------------------------------------------------------------------------
// Stage 2 v2: L2-latency fix. Diagnosis (R7): VGPR=32 forced chunked load
// issue -> ~5 serialized L2 waits; occupancy grid-capped at 15 waves/CU.
// Fix: branch-free (clamped addresses, zero-masked contributions), ALL 24
// loads (12 float2 sn + 12 float nq) staged into registers before any math
// (one latency wait), 2 outputs/thread -> 30 waves/CU.
// ---------------------------------------------------------------------------
__global__ __launch_bounds__(256) void dav_stage2(
    const float2* __restrict__ sn, const float* __restrict__ nq,
    float* __restrict__ out) {
  int idx = blockIdx.x * 256 + threadIdx.x;   // [0, B*D*H*WG2)
  int g  = idx % WG2;
  int h  = (idx / WG2) % H;
  int bd = idx / (WG2 * H);   // b*D + d
  int b  = bd / D;
  int w0 = g * 2;

  const float2* plane  = sn + (size_t)bd * HW;
  const float*  qplane = nq + (size_t)b * HW;

  // Clamped row/col indices + validity masks (zero-padding semantics).
  int hm = (h > 0) ? h - 1 : 0;
  int hp = (h < H - 1) ? h + 1 : H - 1;
  float mt = (h > 0) ? 1.f : 0.f;           // top row mask
  float mb = (h < H - 1) ? 1.f : 0.f;       // bottom row mask
  int cc[4];
  cc[0] = (w0 > 0) ? w0 - 1 : 0;
  cc[1] = w0;
  cc[2] = w0 + 1;
  cc[3] = (w0 + 2 < W) ? w0 + 2 : W - 1;
  float ml = (w0 > 0) ? 1.f : 0.f;          // left col mask
  float mr = (w0 + 2 < W) ? 1.f : 0.f;      // right col mask

  // ---- stage ALL loads (independent, branch-free) ----
  float2 sT[4], sM[4], sB[4];
  float  qT[4], qM[4], qB[4];
#pragma unroll
  for (int j = 0; j < 4; ++j) {
    sT[j] = plane[hm * W + cc[j]];
    sM[j] = plane[h  * W + cc[j]];
    sB[j] = plane[hp * W + cc[j]];
    qT[j] = qplane[hm * W + cc[j]];
    qM[j] = qplane[h  * W + cc[j]];
    qB[j] = qplane[hp * W + cc[j]];
  }

  // ---- column sums (rows masked) ----
  float colS[4], colN[4], colQ[4];
#pragma unroll
  for (int j = 0; j < 4; ++j) {
    colS[j] = mt * sT[j].x + sM[j].x + mb * sB[j].x;
    colN[j] = mt * sT[j].y + sM[j].y + mb * sB[j].y;
    colQ[j] = mt * qT[j]   + qM[j]   + mb * qB[j];
  }

  // ---- two outputs from 4 column sums (edge cols masked) ----
  float dot0 = ml * colS[0] + colS[1] + colS[2];
  float k20  = ml * colN[0] + colN[1] + colN[2];
  float q20  = ml * colQ[0] + colQ[1] + colQ[2];
  float dot1 = colS[1] + colS[2] + mr * colS[3];
  float k21  = colN[1] + colN[2] + mr * colN[3];
  float q21  = colQ[1] + colQ[2] + mr * colQ[3];

  float o0 = dot0 / (fmaxf(sqrtf(q20), EPS) * fmaxf(sqrtf(k20), EPS));
  float o1 = dot1 / (fmaxf(sqrtf(q21), EPS) * fmaxf(sqrtf(k21), EPS));
  *reinterpret_cast<float2*>(out + (size_t)bd * HW + h * W + w0) =
      make_float2(o0, o1);
}

extern "C" void kernel_launch(void* const* d_in, const int* in_sizes, int n_in,
                              void* d_out, int out_size, void* d_ws, size_t ws_size,
                              hipStream_t stream) {
  const float* q = (const float*)d_in[0];               // (B,C,H,W)
  const float* k = (const float*)d_in[1];               // (B,C,H,W,D)
  float* out = (float*)d_out;                           // (B,D,H,W)

  // Workspace layout: sn (float2, NP*D) | nq (float, NP)
  float2* sn = (float2*)d_ws;                           // 7.86 MB
  float*  nq = (float*)(sn + (size_t)NP * D);           // 0.12 MB

  {
    int threads = NP * 16;                  // 16 lanes per pixel -> 491520
    int blocks = threads / 256;             // 1920 (exact)
    dav_stage1<<<blocks, 256, 0, stream>>>(q, k, sn, nq);
  }
  {
    int n = B * D * H * WG2;                // 491520 threads, 2 outputs each
    int blocks = n / 256;                   // 1920 (exact) -> 30 waves/CU
    dav_stage2<<<blocks, 256, 0, stream>>>(sn, nq, out);
  }
}